// Round 2
// baseline (426.151 us; speedup 1.0000x reference)
//
#include <hip/hip_runtime.h>

typedef unsigned short u16;
typedef unsigned int   u32;
typedef unsigned long long u64;
typedef __attribute__((ext_vector_type(4))) int   i32x4;
typedef __attribute__((ext_vector_type(4))) float f32x4;
typedef __attribute__((ext_vector_type(8))) short s16x8;

#define NROWS 98304L   // B*A
#define LDF   512      // feat row stride (250 h | 6 pad | 250 gat | 6 pad)

__device__ __forceinline__ u16 f2bf(float x) {
  union { float f; u32 u; } v; v.f = x;
  return (u16)((v.u + 0x7FFFu + ((v.u >> 16) & 1u)) >> 16);
}
__device__ __forceinline__ float bf2f(u16 b) {
  union { float f; u32 u; } v; v.u = ((u32)b) << 16;
  return v.f;
}

// ---------------- weight prep: transpose + zero-pad to bf16 ----------------
__global__ __launch_bounds__(256)
void prep_weights(const float* __restrict__ W_emb, const float* __restrict__ b_emb,
                  const float* __restrict__ W_gat, const float* __restrict__ W1,
                  const float* __restrict__ b1, const float* __restrict__ V1,
                  const float* __restrict__ vb1,
                  u16* __restrict__ Wemb_t, u16* __restrict__ Wgat_t,
                  u16* __restrict__ W1V1_t, float* __restrict__ bembp,
                  float* __restrict__ b1vb1)
{
  const int idx = blockIdx.x * 256 + threadIdx.x;
  const int stride = gridDim.x * 256;
  // Wemb_t[n][k], n<256 (pad 250..255), k<128
  for (int t = idx; t < 256 * 128; t += stride) {
    int n = t >> 7, k = t & 127;
    Wemb_t[t] = f2bf(n < 250 ? W_emb[k * 250 + n] : 0.f);
  }
  // Wgat_t[h][e][d] = W_gat[h][d][e], 256x256 padded
  for (int t = idx; t < 3 * 256 * 256; t += stride) {
    int h = t >> 16, rem = t & 65535, e = rem >> 8, d = rem & 255;
    Wgat_t[t] = f2bf((e < 250 && d < 250) ? W_gat[(h * 250 + d) * 250 + e] : 0.f);
  }
  // W1V1_t[n][k]: n<256 actor col, else critic col; k maps feat-pad rows
  for (int t = idx; t < 512 * 512; t += stride) {
    int n = t >> 9, k = t & 511;
    const float* src = (n < 256) ? W1 : V1;
    int col = n & 255;
    float v = 0.f;
    if (k < 250) v = src[k * 256 + col];
    else if (k >= 256 && k < 506) v = src[(k - 6) * 256 + col];
    W1V1_t[t] = f2bf(v);
  }
  for (int t = idx; t < 512; t += stride) b1vb1[t] = (t < 256) ? b1[t] : vb1[t - 256];
  for (int t = idx; t < 256; t += stride) bembp[t] = (t < 250) ? b_emb[t] : 0.f;
}

// ---------------- x -> bf16 ----------------
__global__ __launch_bounds__(256)
void cvt_x(const float* __restrict__ x, u16* __restrict__ xb)
{
  const long n = NROWS * 128;
  long i = ((long)blockIdx.x * 256 + threadIdx.x) * 8;
  const long stride = (long)gridDim.x * 256 * 8;
  for (; i < n; i += stride) {
    f32x4 a = *(const f32x4*)(x + i);
    f32x4 b = *(const f32x4*)(x + i + 4);
    i32x4 o;
    o[0] = (int)((u32)f2bf(a[0]) | ((u32)f2bf(a[1]) << 16));
    o[1] = (int)((u32)f2bf(a[2]) | ((u32)f2bf(a[3]) << 16));
    o[2] = (int)((u32)f2bf(b[0]) | ((u32)f2bf(b[1]) << 16));
    o[3] = (int)((u32)f2bf(b[2]) | ((u32)f2bf(b[3]) << 16));
    *(i32x4*)(xb + i) = o;
  }
}

// ---------------- bf16 GEMM: C[M][ldc] = A[M][lda(cols 0..K)] * Bt[N][ldb]^T ----
// BM=BN=128, BK=64, 256 threads (4 waves, 2x2 of 64x64), LDS pad 64->72 elems.
template<int KSTEPS, int EPI>   // EPI: 0 = raw bf16 store, 1 = +bias, relu
__global__ __launch_bounds__(256, 2)
void gemm_bf16(const u16* __restrict__ A, int lda,
               const u16* __restrict__ B, int ldb, long strideB,
               u16* __restrict__ C, int ldc, long strideC,
               const float* __restrict__ bias)
{
  __shared__ __align__(16) u16 At[128][72];
  __shared__ __align__(16) u16 Bt[128][72];
  const int tid = threadIdx.x;
  const int w = tid >> 6, lane = tid & 63;
  const int fl = lane & 15, fh = lane >> 4;
  const int wr = (w >> 1) * 64, wc = (w & 1) * 64;
  const int srow = tid >> 3, soff = (tid & 7) * 8;

  const u16* Ab = A + (long)blockIdx.x * 128 * lda;
  const u16* Bb = B + (long)blockIdx.z * strideB + (long)blockIdx.y * 128 * ldb;
  u16* Cb = C + (long)blockIdx.z * strideC + (long)blockIdx.x * 128 * ldc + blockIdx.y * 128;
  const float* biasb = bias + blockIdx.y * 128;

  f32x4 acc[4][4];
  #pragma unroll
  for (int m = 0; m < 4; m++)
    #pragma unroll
    for (int n = 0; n < 4; n++)
      acc[m][n] = f32x4{0.f, 0.f, 0.f, 0.f};

  i32x4 av[4], bv[4];
  #pragma unroll
  for (int i = 0; i < 4; i++) {
    av[i] = *(const i32x4*)(Ab + (long)(i * 32 + srow) * lda + soff);
    bv[i] = *(const i32x4*)(Bb + (long)(i * 32 + srow) * ldb + soff);
  }
  for (int ks = 0;;) {
    __syncthreads();
    #pragma unroll
    for (int i = 0; i < 4; i++) {
      *(i32x4*)(&At[i * 32 + srow][soff]) = av[i];
      *(i32x4*)(&Bt[i * 32 + srow][soff]) = bv[i];
    }
    __syncthreads();
    ++ks;
    if (ks < KSTEPS) {
      #pragma unroll
      for (int i = 0; i < 4; i++) {
        av[i] = *(const i32x4*)(Ab + (long)(i * 32 + srow) * lda + ks * 64 + soff);
        bv[i] = *(const i32x4*)(Bb + (long)(i * 32 + srow) * ldb + ks * 64 + soff);
      }
    }
    #pragma unroll
    for (int kk = 0; kk < 2; kk++) {
      s16x8 af[4], bf[4];
      #pragma unroll
      for (int m = 0; m < 4; m++) af[m] = *(const s16x8*)(&At[wr + m * 16 + fl][kk * 32 + fh * 8]);
      #pragma unroll
      for (int n = 0; n < 4; n++) bf[n] = *(const s16x8*)(&Bt[wc + n * 16 + fl][kk * 32 + fh * 8]);
      #pragma unroll
      for (int m = 0; m < 4; m++)
        #pragma unroll
        for (int n = 0; n < 4; n++)
          acc[m][n] = __builtin_amdgcn_mfma_f32_16x16x32_bf16(af[m], bf[n], acc[m][n], 0, 0, 0);
    }
    if (ks >= KSTEPS) break;
  }
  #pragma unroll
  for (int m = 0; m < 4; m++) {
    const int r0 = wr + m * 16 + fh * 4;
    #pragma unroll
    for (int n = 0; n < 4; n++) {
      const int col = wc + n * 16 + fl;
      float bvv = 0.f;
      if constexpr (EPI == 1) bvv = biasb[col];
      f32x4 v = acc[m][n];
      #pragma unroll
      for (int r = 0; r < 4; r++) {
        float xv = v[r];
        if constexpr (EPI == 1) xv = fmaxf(xv + bvv, 0.f);
        Cb[(long)(r0 + r) * ldc + col] = f2bf(xv);
      }
    }
  }
}

// ---------------- per-graph attention + gat, writes feat cols 256..511 --------
__global__ __launch_bounds__(256)
void attn_gat(const u16* __restrict__ Wh, const float* __restrict__ a_l,
              const float* __restrict__ a_r, u16* __restrict__ feat)
{
  const int w = threadIdx.x >> 6, lane = threadIdx.x & 63;
  const long g = (long)blockIdx.x * 4 + w;   // one wave per graph
  const int c0 = lane * 4;                    // 4 cols per lane (0..255)
  float gacc[6][4];
  #pragma unroll
  for (int i = 0; i < 6; i++)
    #pragma unroll
    for (int q = 0; q < 4; q++) gacc[i][q] = 0.f;

  #pragma unroll
  for (int h = 0; h < 3; h++) {
    float whf[6][4];
    #pragma unroll
    for (int i = 0; i < 6; i++) {
      u64 v = *(const u64*)(Wh + (((long)h * NROWS + g * 6 + i) << 8) + c0);
      whf[i][0] = bf2f((u16)v);
      whf[i][1] = bf2f((u16)(v >> 16));
      whf[i][2] = bf2f((u16)(v >> 32));
      whf[i][3] = bf2f((u16)(v >> 48));
    }
    float alv[4], arv[4];
    #pragma unroll
    for (int q = 0; q < 4; q++) {
      int c = c0 + q;
      alv[q] = (c < 250) ? a_l[h * 250 + c] : 0.f;
      arv[q] = (c < 250) ? a_r[h * 250 + c] : 0.f;
    }
    float pel[6], per[6];
    #pragma unroll
    for (int i = 0; i < 6; i++) {
      pel[i] = whf[i][0] * alv[0] + whf[i][1] * alv[1] + whf[i][2] * alv[2] + whf[i][3] * alv[3];
      per[i] = whf[i][0] * arv[0] + whf[i][1] * arv[1] + whf[i][2] * arv[2] + whf[i][3] * arv[3];
    }
    #pragma unroll
    for (int off = 1; off < 64; off <<= 1) {
      #pragma unroll
      for (int i = 0; i < 6; i++) {
        pel[i] += __shfl_xor(pel[i], off, 64);
        per[i] += __shfl_xor(per[i], off, 64);
      }
    }
    #pragma unroll
    for (int i = 0; i < 6; i++) {
      float e[6]; float mx = -1e30f;
      #pragma unroll
      for (int j = 0; j < 6; j++) {
        float t = pel[i] + per[j];
        t = (t > 0.f) ? t : 0.2f * t;      // leaky_relu 0.2
        e[j] = t; mx = fmaxf(mx, t);
      }
      float s = 0.f;
      #pragma unroll
      for (int j = 0; j < 6; j++) { e[j] = __expf(e[j] - mx); s += e[j]; }
      float inv = 1.f / s;
      #pragma unroll
      for (int j = 0; j < 6; j++) {
        float a = e[j] * inv;
        #pragma unroll
        for (int q = 0; q < 4; q++) gacc[i][q] += a * whf[j][q];
      }
    }
  }
  #pragma unroll
  for (int i = 0; i < 6; i++) {
    const float k = 1.f / 3.f;
    u64 o = (u64)f2bf(gacc[i][0] * k)
          | ((u64)f2bf(gacc[i][1] * k) << 16)
          | ((u64)f2bf(gacc[i][2] * k) << 32)
          | ((u64)f2bf(gacc[i][3] * k) << 48);
    *(u64*)(feat + (g * 6 + i) * LDF + 256 + c0) = o;
  }
}

// ---------------- heads: hidden[512] -> softmax(5) | value, one wave per row --
__global__ __launch_bounds__(256)
void heads(const u16* __restrict__ hidden, const float* __restrict__ W2,
           const float* __restrict__ b2, const float* __restrict__ V2,
           const float* __restrict__ vb2, float* __restrict__ out)
{
  const int w = threadIdx.x >> 6, lane = threadIdx.x & 63;
  const bool actor = lane < 32;
  const int kb = (lane & 31) * 8;
  float wreg[40];
  if (actor) {
    #pragma unroll
    for (int i = 0; i < 8; i++)
      #pragma unroll
      for (int j = 0; j < 5; j++) wreg[i * 5 + j] = W2[(kb + i) * 5 + j];
  } else {
    #pragma unroll
    for (int i = 0; i < 8; i++) wreg[i] = V2[kb + i];
  }
  float b2v[5];
  #pragma unroll
  for (int j = 0; j < 5; j++) b2v[j] = b2[j];
  const float vb2v = vb2[0];

  const long base = ((long)blockIdx.x * 4 + w) * 6;
  for (int rr = 0; rr < 6; ++rr) {
    const long row = base + rr;
    const u16* hp = hidden + row * 512 + (actor ? kb : 256 + kb);
    i32x4 hv4 = *(const i32x4*)hp;
    float hv[8];
    #pragma unroll
    for (int q = 0; q < 4; q++) {
      u32 u = (u32)hv4[q];
      hv[2 * q]     = bf2f((u16)u);
      hv[2 * q + 1] = bf2f((u16)(u >> 16));
    }
    float p[6] = {0.f, 0.f, 0.f, 0.f, 0.f, 0.f};
    if (actor) {
      #pragma unroll
      for (int j = 0; j < 5; j++) {
        float s = 0.f;
        #pragma unroll
        for (int i = 0; i < 8; i++) s += hv[i] * wreg[i * 5 + j];
        p[j] = s;
      }
    } else {
      float s = 0.f;
      #pragma unroll
      for (int i = 0; i < 8; i++) s += hv[i] * wreg[i];
      p[5] = s;
    }
    #pragma unroll
    for (int off = 1; off < 64; off <<= 1)
      #pragma unroll
      for (int j = 0; j < 6; j++) p[j] += __shfl_xor(p[j], off, 64);
    if (lane < 6) {
      float val;
      if (lane < 5) {
        float lg[5]; float mx = -1e30f;
        #pragma unroll
        for (int j = 0; j < 5; j++) { lg[j] = p[j] + b2v[j]; mx = fmaxf(mx, lg[j]); }
        float s = 0.f;
        #pragma unroll
        for (int j = 0; j < 5; j++) s += __expf(lg[j] - mx);
        val = __expf(lg[lane] - mx) / s;
      } else {
        val = p[5] + vb2v;
      }
      out[row * 6 + lane] = val;
    }
  }
}

// ---------------- launch ----------------
extern "C" void kernel_launch(void* const* d_in, const int* in_sizes, int n_in,
                              void* d_out, int out_size, void* d_ws, size_t ws_size,
                              hipStream_t stream)
{
  const float* x     = (const float*)d_in[0];
  const float* W_emb = (const float*)d_in[1];
  const float* b_emb = (const float*)d_in[2];
  const float* W_gat = (const float*)d_in[3];
  const float* a_l   = (const float*)d_in[4];
  const float* a_r   = (const float*)d_in[5];
  const float* W1    = (const float*)d_in[6];
  const float* b1    = (const float*)d_in[7];
  const float* W2    = (const float*)d_in[8];
  const float* b2    = (const float*)d_in[9];
  const float* V1    = (const float*)d_in[10];
  const float* vb1   = (const float*)d_in[11];
  const float* V2    = (const float*)d_in[12];
  const float* vb2   = (const float*)d_in[13];

  char* ws = (char*)d_ws;
  u16* feat = (u16*)ws;                       // [98304][512] bf16 = 100,663,296 B
  char* r2  = ws + 100663296L;                // shared region, lifetimes disjoint:
  u16* xb   = (u16*)r2;                       //   [98304][128] (cvt_x -> gemm1)
  u16* Whb  = (u16*)r2;                       //   [3][98304][256] (gemm2 -> attn)
  u16* hid  = (u16*)r2;                       //   [98304][512] (gemm3 -> heads)
  char* wt  = r2 + 150994944L;
  u16*   Wemb_t = (u16*)wt;                   // 256*128
  u16*   Wgat_t = (u16*)(wt + 65536);         // 3*256*256
  u16*   W1V1_t = (u16*)(wt + 458752);        // 512*512
  float* b1vb1  = (float*)(wt + 983040);      // 512
  float* bembp  = (float*)(wt + 985088);      // 256

  prep_weights<<<256, 256, 0, stream>>>(W_emb, b_emb, W_gat, W1, b1, V1, vb1,
                                        Wemb_t, Wgat_t, W1V1_t, bembp, b1vb1);
  cvt_x<<<2048, 256, 0, stream>>>(x, xb);
  // h = relu(x @ W_emb + b) -> feat[:,0:256]
  gemm_bf16<2, 1><<<dim3(768, 2, 1), 256, 0, stream>>>(xb, 128, Wemb_t, 128, 0L,
                                                       feat, 512, 0L, bembp);
  // Wh[h] = h @ W_gat[h]  (batched over z=3)
  gemm_bf16<4, 0><<<dim3(768, 2, 3), 256, 0, stream>>>(feat, 512, Wgat_t, 256, 65536L,
                                                       Whb, 256, 25165824L, bembp);
  // attention + gat -> feat[:,256:512]
  attn_gat<<<4096, 256, 0, stream>>>(Whb, a_l, a_r, feat);
  // hidden = relu(feat @ [W1|V1] + [b1|vb1])
  gemm_bf16<8, 1><<<dim3(768, 4, 1), 256, 0, stream>>>(feat, 512, W1V1_t, 512, 0L,
                                                       hid, 512, 0L, b1vb1);
  // probs/value
  heads<<<4096, 256, 0, stream>>>(hid, W2, b2, V2, vb2, (float*)d_out);
}

// Round 4
// 390.323 us; speedup vs baseline: 1.0918x; 1.0918x over previous
//
#include <hip/hip_runtime.h>

typedef unsigned short u16;
typedef unsigned int   u32;
typedef unsigned long long u64;
typedef __attribute__((ext_vector_type(4))) int   i32x4;
typedef __attribute__((ext_vector_type(4))) float f32x4;
typedef __attribute__((ext_vector_type(8))) short s16x8;

#define NROWS 98304L   // B*A
#define LDF   512      // feat row stride (250 h | 6 pad | 250 gat | 6 pad)

__device__ __forceinline__ u16 f2bf(float x) {
  union { float f; u32 u; } v; v.f = x;
  return (u16)((v.u + 0x7FFFu + ((v.u >> 16) & 1u)) >> 16);
}
__device__ __forceinline__ float bf2f(u16 b) {
  union { float f; u32 u; } v; v.u = ((u32)b) << 16;
  return v.f;
}

// async global->LDS, 16B per lane; LDS dest = uniform base + lane*16 (m104)
__device__ __forceinline__ void gload_lds16(const u16* g, u16* l) {
  __builtin_amdgcn_global_load_lds(
      (const __attribute__((address_space(1))) unsigned int*)g,
      (__attribute__((address_space(3))) unsigned int*)l, 16, 0, 0);
}

// ---------------- weight prep: transpose + zero-pad to bf16 ----------------
// Wgat_t rows e=250/251 get u_l[h]=W_gat[h]@a_l[h], u_r[h] so the Wh GEMM
// emits el/er as free output columns (el = h . (W_gat @ a_l)).
__global__ __launch_bounds__(256)
void prep_weights(const float* __restrict__ W_emb, const float* __restrict__ b_emb,
                  const float* __restrict__ W_gat, const float* __restrict__ a_l,
                  const float* __restrict__ a_r, const float* __restrict__ W1,
                  const float* __restrict__ b1, const float* __restrict__ V1,
                  const float* __restrict__ vb1,
                  u16* __restrict__ Wemb_t, u16* __restrict__ Wgat_t,
                  u16* __restrict__ W1V1_t, float* __restrict__ bembp,
                  float* __restrict__ b1vb1)
{
  const int idx = blockIdx.x * 256 + threadIdx.x;
  const int stride = gridDim.x * 256;
  // Wemb_t[n][k], n<256 (pad 250..255), k<128
  for (int t = idx; t < 256 * 128; t += stride) {
    int n = t >> 7, k = t & 127;
    Wemb_t[t] = f2bf(n < 250 ? W_emb[k * 250 + n] : 0.f);
  }
  // Wgat_t[h][e][d] = W_gat[h][d][e] (256x256 padded); rows 250/251 = u_l/u_r
  for (int t = idx; t < 3 * 256 * 256; t += stride) {
    int h = t >> 16, rem = t & 65535, e = rem >> 8, d = rem & 255;
    float v = 0.f;
    if (e < 250 && d < 250) {
      v = W_gat[(h * 250 + d) * 250 + e];
    } else if ((e == 250 || e == 251) && d < 250) {
      const float* av = ((e == 250) ? a_l : a_r) + h * 250;
      const float* wrow = W_gat + ((long)h * 250 + d) * 250;
      float s = 0.f;
      for (int q = 0; q < 250; q++) s += wrow[q] * av[q];
      v = s;
    }
    Wgat_t[t] = f2bf(v);
  }
  // W1V1_t[n][k]: n<256 actor col, else critic col; k maps feat-pad rows
  for (int t = idx; t < 512 * 512; t += stride) {
    int n = t >> 9, k = t & 511;
    const float* src = (n < 256) ? W1 : V1;
    int col = n & 255;
    float v = 0.f;
    if (k < 250) v = src[k * 256 + col];
    else if (k >= 256 && k < 506) v = src[(k - 6) * 256 + col];
    W1V1_t[t] = f2bf(v);
  }
  for (int t = idx; t < 512; t += stride) b1vb1[t] = (t < 256) ? b1[t] : vb1[t - 256];
  for (int t = idx; t < 256; t += stride) bembp[t] = (t < 250) ? b_emb[t] : 0.f;
}

// ---------------- x -> bf16 ----------------
__global__ __launch_bounds__(256)
void cvt_x(const float* __restrict__ x, u16* __restrict__ xb)
{
  const long n = NROWS * 128;
  long i = ((long)blockIdx.x * 256 + threadIdx.x) * 8;
  const long stride = (long)gridDim.x * 256 * 8;
  for (; i < n; i += stride) {
    f32x4 a = *(const f32x4*)(x + i);
    f32x4 b = *(const f32x4*)(x + i + 4);
    i32x4 o;
    o[0] = (int)((u32)f2bf(a[0]) | ((u32)f2bf(a[1]) << 16));
    o[1] = (int)((u32)f2bf(a[2]) | ((u32)f2bf(a[3]) << 16));
    o[2] = (int)((u32)f2bf(b[0]) | ((u32)f2bf(b[1]) << 16));
    o[3] = (int)((u32)f2bf(b[2]) | ((u32)f2bf(b[3]) << 16));
    *(i32x4*)(xb + i) = o;
  }
}

// ---------------- bf16 GEMM: C[M][ldc] = A[M][lda] * Bt[N][ldb]^T ----
// BM=BN=128, BK=64, 256 threads (4 waves, 2x2 of 64x64).
// global_load_lds(16B) staging into linear [128][64] LDS with both-sides
// XOR swizzle (rule #21): source col pre-swizzled, ds_read applies same XOR.
template<int KSTEPS, int EPI>   // EPI: 0 = raw bf16 store, 1 = +bias, relu
__global__ __launch_bounds__(256, 2)
void gemm_bf16(const u16* __restrict__ A, int lda,
               const u16* __restrict__ B, int ldb, long strideB,
               u16* __restrict__ C, int ldc, long strideC,
               const float* __restrict__ bias)
{
  __shared__ __align__(16) u16 At[128 * 64];
  __shared__ __align__(16) u16 Bt[128 * 64];
  const int tid = threadIdx.x;
  const int w = tid >> 6, lane = tid & 63;
  const int fl = lane & 15, fh = lane >> 4;
  const int wr = (w >> 1) * 64, wc = (w & 1) * 64;
  const int srow = lane >> 3;                        // 0..7 row within 8-row chunk
  const int scol = (((lane & 7) ^ srow) << 3);       // inverse-swizzled source col
  const int swz = (fl & 7) << 3;                     // ds_read swizzle

  const u16* Ab = A + (long)blockIdx.x * 128 * lda;
  const u16* Bb = B + (long)blockIdx.z * strideB + (long)blockIdx.y * 128 * ldb;
  u16* Cb = C + (long)blockIdx.z * strideC + (long)blockIdx.x * 128 * ldc + blockIdx.y * 128;
  const float* biasb = bias + blockIdx.y * 128;

  f32x4 acc[4][4];
  #pragma unroll
  for (int m = 0; m < 4; m++)
    #pragma unroll
    for (int n = 0; n < 4; n++)
      acc[m][n] = f32x4{0.f, 0.f, 0.f, 0.f};

  for (int ks = 0; ks < KSTEPS; ks++) {
    __syncthreads();                     // prev tile's ds_reads complete
    #pragma unroll
    for (int c = 0; c < 4; c++) {
      const int row = w * 32 + c * 8 + srow;
      gload_lds16(Ab + (long)row * lda + ks * 64 + scol, At + (w * 4 + c) * 512);
      gload_lds16(Bb + (long)row * ldb + ks * 64 + scol, Bt + (w * 4 + c) * 512);
    }
    __syncthreads();                     // compiler drains vmcnt(0) before barrier
    #pragma unroll
    for (int kk = 0; kk < 2; kk++) {
      s16x8 af[4], bfr[4];
      #pragma unroll
      for (int m = 0; m < 4; m++)
        af[m] = *(const s16x8*)(At + (wr + m * 16 + fl) * 64 + ((kk * 32 + fh * 8) ^ swz));
      #pragma unroll
      for (int n = 0; n < 4; n++)
        bfr[n] = *(const s16x8*)(Bt + (wc + n * 16 + fl) * 64 + ((kk * 32 + fh * 8) ^ swz));
      #pragma unroll
      for (int m = 0; m < 4; m++)
        #pragma unroll
        for (int n = 0; n < 4; n++)
          acc[m][n] = __builtin_amdgcn_mfma_f32_16x16x32_bf16(af[m], bfr[n], acc[m][n], 0, 0, 0);
    }
  }
  #pragma unroll
  for (int m = 0; m < 4; m++) {
    const int r0 = wr + m * 16 + fh * 4;
    #pragma unroll
    for (int n = 0; n < 4; n++) {
      const int col = wc + n * 16 + fl;
      float bvv = 0.f;
      if constexpr (EPI == 1) bvv = biasb[col];
      f32x4 v = acc[m][n];
      #pragma unroll
      for (int r = 0; r < 4; r++) {
        float xv = v[r];
        if constexpr (EPI == 1) xv = fmaxf(xv + bvv, 0.f);
        Cb[(long)(r0 + r) * ldc + col] = f2bf(xv);
      }
    }
  }
}

// ---------------- per-graph attention + gat, writes feat cols 256..511 --------
// el/er arrive as Wh columns 250/251 (lane 62, q=2/3) — no reductions needed.
__global__ __launch_bounds__(256)
void attn_gat(const u16* __restrict__ Wh, u16* __restrict__ feat)
{
  const int w = threadIdx.x >> 6, lane = threadIdx.x & 63;
  const long g = (long)blockIdx.x * 4 + w;   // one wave per graph
  const int c0 = lane * 4;                    // 4 cols per lane (0..255)

  u64 raw[3][6];
  #pragma unroll
  for (int h = 0; h < 3; h++)
    #pragma unroll
    for (int i = 0; i < 6; i++)
      raw[h][i] = *(const u64*)(Wh + (((long)h * NROWS + g * 6 + i) << 8) + c0);

  float gacc[6][4];
  #pragma unroll
  for (int i = 0; i < 6; i++)
    #pragma unroll
    for (int q = 0; q < 4; q++) gacc[i][q] = 0.f;

  #pragma unroll
  for (int h = 0; h < 3; h++) {
    float whf[6][4];
    #pragma unroll
    for (int i = 0; i < 6; i++) {
      u64 v = raw[h][i];
      whf[i][0] = bf2f((u16)v);
      whf[i][1] = bf2f((u16)(v >> 16));
      whf[i][2] = bf2f((u16)(v >> 32));
      whf[i][3] = bf2f((u16)(v >> 48));
    }
    float el[6], er[6];
    #pragma unroll
    for (int i = 0; i < 6; i++) {
      el[i] = __shfl(whf[i][2], 62, 64);   // col 250
      er[i] = __shfl(whf[i][3], 62, 64);   // col 251
    }
    #pragma unroll
    for (int i = 0; i < 6; i++) {
      float e[6]; float mx = -1e30f;
      #pragma unroll
      for (int j = 0; j < 6; j++) {
        float t = el[i] + er[j];
        t = (t > 0.f) ? t : 0.2f * t;      // leaky_relu 0.2
        e[j] = t; mx = fmaxf(mx, t);
      }
      float s = 0.f;
      #pragma unroll
      for (int j = 0; j < 6; j++) { e[j] = __expf(e[j] - mx); s += e[j]; }
      float inv = 1.f / s;
      #pragma unroll
      for (int j = 0; j < 6; j++) {
        float a = e[j] * inv;
        #pragma unroll
        for (int q = 0; q < 4; q++) gacc[i][q] += a * whf[j][q];
      }
    }
  }
  #pragma unroll
  for (int i = 0; i < 6; i++) {
    const float k = 1.f / 3.f;
    u64 o = (u64)f2bf(gacc[i][0] * k)
          | ((u64)f2bf(gacc[i][1] * k) << 16)
          | ((u64)f2bf(gacc[i][2] * k) << 32)
          | ((u64)f2bf(gacc[i][3] * k) << 48);
    *(u64*)(feat + (g * 6 + i) * LDF + 256 + c0) = o;
  }
}

// ---------------- heads: hidden[512] -> softmax(5) | value, one wave per row --
__global__ __launch_bounds__(256)
void heads(const u16* __restrict__ hidden, const float* __restrict__ W2,
           const float* __restrict__ b2, const float* __restrict__ V2,
           const float* __restrict__ vb2, float* __restrict__ out)
{
  const int w = threadIdx.x >> 6, lane = threadIdx.x & 63;
  const bool actor = lane < 32;
  const int kb = (lane & 31) * 8;
  float wreg[40];
  if (actor) {
    #pragma unroll
    for (int i = 0; i < 8; i++)
      #pragma unroll
      for (int j = 0; j < 5; j++) wreg[i * 5 + j] = W2[(kb + i) * 5 + j];
  } else {
    #pragma unroll
    for (int i = 0; i < 8; i++) wreg[i] = V2[kb + i];
  }
  float b2v[5];
  #pragma unroll
  for (int j = 0; j < 5; j++) b2v[j] = b2[j];
  const float vb2v = vb2[0];

  const long base = ((long)blockIdx.x * 4 + w) * 6;
  for (int rr = 0; rr < 6; ++rr) {
    const long row = base + rr;
    const u16* hp = hidden + row * 512 + (actor ? kb : 256 + kb);
    i32x4 hv4 = *(const i32x4*)hp;
    float hv[8];
    #pragma unroll
    for (int q = 0; q < 4; q++) {
      u32 u = (u32)hv4[q];
      hv[2 * q]     = bf2f((u16)u);
      hv[2 * q + 1] = bf2f((u16)(u >> 16));
    }
    float p[6] = {0.f, 0.f, 0.f, 0.f, 0.f, 0.f};
    if (actor) {
      #pragma unroll
      for (int j = 0; j < 5; j++) {
        float s = 0.f;
        #pragma unroll
        for (int i = 0; i < 8; i++) s += hv[i] * wreg[i * 5 + j];
        p[j] = s;
      }
    } else {
      float s = 0.f;
      #pragma unroll
      for (int i = 0; i < 8; i++) s += hv[i] * wreg[i];
      p[5] = s;
    }
    #pragma unroll
    for (int off = 1; off < 64; off <<= 1)
      #pragma unroll
      for (int j = 0; j < 6; j++) p[j] += __shfl_xor(p[j], off, 64);
    if (lane < 6) {
      float val;
      if (lane < 5) {
        float lg[5]; float mx = -1e30f;
        #pragma unroll
        for (int j = 0; j < 5; j++) { lg[j] = p[j] + b2v[j]; mx = fmaxf(mx, lg[j]); }
        float s = 0.f;
        #pragma unroll
        for (int j = 0; j < 5; j++) s += __expf(lg[j] - mx);
        val = __expf(lg[lane] - mx) / s;
      } else {
        val = p[5] + vb2v;
      }
      out[row * 6 + lane] = val;
    }
  }
}

// ---------------- launch ----------------
extern "C" void kernel_launch(void* const* d_in, const int* in_sizes, int n_in,
                              void* d_out, int out_size, void* d_ws, size_t ws_size,
                              hipStream_t stream)
{
  const float* x     = (const float*)d_in[0];
  const float* W_emb = (const float*)d_in[1];
  const float* b_emb = (const float*)d_in[2];
  const float* W_gat = (const float*)d_in[3];
  const float* a_l   = (const float*)d_in[4];
  const float* a_r   = (const float*)d_in[5];
  const float* W1    = (const float*)d_in[6];
  const float* b1    = (const float*)d_in[7];
  const float* W2    = (const float*)d_in[8];
  const float* b2    = (const float*)d_in[9];
  const float* V1    = (const float*)d_in[10];
  const float* vb1   = (const float*)d_in[11];
  const float* V2    = (const float*)d_in[12];
  const float* vb2   = (const float*)d_in[13];

  char* ws = (char*)d_ws;
  u16* feat = (u16*)ws;                       // [98304][512] bf16 = 100,663,296 B
  char* r2  = ws + 100663296L;                // shared region, lifetimes disjoint:
  u16* xb   = (u16*)r2;                       //   [98304][128] (cvt_x -> gemm1)
  u16* Whb  = (u16*)r2;                       //   [3][98304][256] (gemm2 -> attn)
  u16* hid  = (u16*)r2;                       //   [98304][512] (gemm3 -> heads)
  char* wt  = r2 + 150994944L;
  u16*   Wemb_t = (u16*)wt;                   // 256*128
  u16*   Wgat_t = (u16*)(wt + 65536);         // 3*256*256
  u16*   W1V1_t = (u16*)(wt + 458752);        // 512*512
  float* b1vb1  = (float*)(wt + 983040);      // 512
  float* bembp  = (float*)(wt + 985088);      // 256

  prep_weights<<<256, 256, 0, stream>>>(W_emb, b_emb, W_gat, a_l, a_r, W1, b1, V1, vb1,
                                        Wemb_t, Wgat_t, W1V1_t, bembp, b1vb1);
  cvt_x<<<2048, 256, 0, stream>>>(x, xb);
  // h = relu(x @ W_emb + b) -> feat[:,0:256]
  gemm_bf16<2, 1><<<dim3(768, 2, 1), 256, 0, stream>>>(xb, 128, Wemb_t, 128, 0L,
                                                       feat, 512, 0L, bembp);
  // Wh[h] = h @ W_gat[h]  (batched over z=3); cols 250/251 = el/er
  gemm_bf16<4, 0><<<dim3(768, 2, 3), 256, 0, stream>>>(feat, 512, Wgat_t, 256, 65536L,
                                                       Whb, 256, 25165824L, bembp);
  // attention + gat -> feat[:,256:512]
  attn_gat<<<4096, 256, 0, stream>>>(Whb, feat);
  // hidden = relu(feat @ [W1|V1] + [b1|vb1])
  gemm_bf16<8, 1><<<dim3(768, 4, 1), 256, 0, stream>>>(feat, 512, W1V1_t, 512, 0L,
                                                       hid, 512, 0L, b1vb1);
  // probs/value
  heads<<<4096, 256, 0, stream>>>(hid, W2, b2, V2, vb2, (float*)d_out);
}

// Round 5
// 364.385 us; speedup vs baseline: 1.1695x; 1.0712x over previous
//
#include <hip/hip_runtime.h>

typedef unsigned short u16;
typedef unsigned int   u32;
typedef unsigned long long u64;
typedef __attribute__((ext_vector_type(4))) int   i32x4;
typedef __attribute__((ext_vector_type(4))) float f32x4;
typedef __attribute__((ext_vector_type(8))) short s16x8;

#define NROWS 98304L   // B*A
#define LDF   512      // feat row stride (250 h | 6 pad | 250 gat | 6 pad)

__device__ __forceinline__ u16 f2bf(float x) {
  union { float f; u32 u; } v; v.f = x;
  return (u16)((v.u + 0x7FFFu + ((v.u >> 16) & 1u)) >> 16);
}
__device__ __forceinline__ float bf2f(u16 b) {
  union { float f; u32 u; } v; v.u = ((u32)b) << 16;
  return v.f;
}

// async global->LDS, 16B per lane; LDS dest = wave-uniform base + lane*16 (m104)
__device__ __forceinline__ void gload_lds16(const u16* g, u16* l) {
  __builtin_amdgcn_global_load_lds(
      (const __attribute__((address_space(1))) unsigned int*)g,
      (__attribute__((address_space(3))) unsigned int*)l, 16, 0, 0);
}

// ---------------- weight prep: transpose + zero-pad to bf16 ----------------
// Wgat_t rows e=250/251 get u_l[h]=W_gat[h]@a_l[h], u_r[h] so the Wh GEMM
// emits el/er as free output columns (el = h . (W_gat @ a_l)).
__global__ __launch_bounds__(256)
void prep_weights(const float* __restrict__ W_emb, const float* __restrict__ b_emb,
                  const float* __restrict__ W_gat, const float* __restrict__ a_l,
                  const float* __restrict__ a_r, const float* __restrict__ W1,
                  const float* __restrict__ b1, const float* __restrict__ V1,
                  const float* __restrict__ vb1,
                  u16* __restrict__ Wemb_t, u16* __restrict__ Wgat_t,
                  u16* __restrict__ W1V1_t, float* __restrict__ bembp,
                  float* __restrict__ b1vb1)
{
  const int idx = blockIdx.x * 256 + threadIdx.x;
  const int stride = gridDim.x * 256;
  // Wemb_t[n][k], n<256 (pad 250..255), k<128
  for (int t = idx; t < 256 * 128; t += stride) {
    int n = t >> 7, k = t & 127;
    Wemb_t[t] = f2bf(n < 250 ? W_emb[k * 250 + n] : 0.f);
  }
  // Wgat_t[h][e][d] = W_gat[h][d][e] (256x256 padded); rows 250/251 = u_l/u_r
  for (int t = idx; t < 3 * 256 * 256; t += stride) {
    int h = t >> 16, rem = t & 65535, e = rem >> 8, d = rem & 255;
    float v = 0.f;
    if (e < 250 && d < 250) {
      v = W_gat[(h * 250 + d) * 250 + e];
    } else if ((e == 250 || e == 251) && d < 250) {
      const float* av = ((e == 250) ? a_l : a_r) + h * 250;
      const float* wrow = W_gat + ((long)h * 250 + d) * 250;
      float s = 0.f;
      for (int q = 0; q < 250; q++) s += wrow[q] * av[q];
      v = s;
    }
    Wgat_t[t] = f2bf(v);
  }
  // W1V1_t[n][k]: n<256 actor col, else critic col; k maps feat-pad rows
  for (int t = idx; t < 512 * 512; t += stride) {
    int n = t >> 9, k = t & 511;
    const float* src = (n < 256) ? W1 : V1;
    int col = n & 255;
    float v = 0.f;
    if (k < 250) v = src[k * 256 + col];
    else if (k >= 256 && k < 506) v = src[(k - 6) * 256 + col];
    W1V1_t[t] = f2bf(v);
  }
  for (int t = idx; t < 512; t += stride) b1vb1[t] = (t < 256) ? b1[t] : vb1[t - 256];
  for (int t = idx; t < 256; t += stride) bembp[t] = (t < 250) ? b_emb[t] : 0.f;
}

// ---------------- x -> bf16 ----------------
__global__ __launch_bounds__(256)
void cvt_x(const float* __restrict__ x, u16* __restrict__ xb)
{
  const long n = NROWS * 128;
  long i = ((long)blockIdx.x * 256 + threadIdx.x) * 8;
  const long stride = (long)gridDim.x * 256 * 8;
  for (; i < n; i += stride) {
    f32x4 a = *(const f32x4*)(x + i);
    f32x4 b = *(const f32x4*)(x + i + 4);
    i32x4 o;
    o[0] = (int)((u32)f2bf(a[0]) | ((u32)f2bf(a[1]) << 16));
    o[1] = (int)((u32)f2bf(a[2]) | ((u32)f2bf(a[3]) << 16));
    o[2] = (int)((u32)f2bf(b[0]) | ((u32)f2bf(b[1]) << 16));
    o[3] = (int)((u32)f2bf(b[2]) | ((u32)f2bf(b[3]) << 16));
    *(i32x4*)(xb + i) = o;
  }
}

// ---------------- bf16 GEMM: C[M][ldc] = A[M][lda] * Bt[N][ldb]^T ----
// BM=BN=128, BK=64, 256 threads (4 waves, 2x2 of 64x64).
// Grid packed as (nb*nz, mblocks): consecutive blocks share the A-tile
// (L2/L3 reuse); global_load_lds(16B) staging, both-sides XOR swizzle.
template<int KSTEPS, int EPI>   // EPI: 0 = raw bf16 store, 1 = +bias, relu
__global__ __launch_bounds__(256, 2)
void gemm_bf16(const u16* __restrict__ A, int lda,
               const u16* __restrict__ B, int ldb, long strideB,
               u16* __restrict__ C, int ldc, long strideC,
               const float* __restrict__ bias, int nb)
{
  __shared__ __align__(16) u16 At[128 * 64];
  __shared__ __align__(16) u16 Bt[128 * 64];
  const int tid = threadIdx.x;
  const int w = tid >> 6, lane = tid & 63;
  const int fl = lane & 15, fh = lane >> 4;
  const int wr = (w >> 1) * 64, wc = (w & 1) * 64;
  const int srow = lane >> 3;                        // 0..7 row within 8-row chunk
  const int scol = (((lane & 7) ^ srow) << 3);       // inverse-swizzled source col
  const int swz = (fl & 7) << 3;                     // ds_read swizzle

  const int nidx = blockIdx.x % nb;
  const int zidx = blockIdx.x / nb;
  const int midx = blockIdx.y;

  const u16* Ab = A + (long)midx * 128 * lda;
  const u16* Bb = B + (long)zidx * strideB + (long)nidx * 128 * ldb;
  u16* Cb = C + (long)zidx * strideC + (long)midx * 128 * ldc + nidx * 128;
  const float* biasb = bias + nidx * 128;

  f32x4 acc[4][4];
  #pragma unroll
  for (int m = 0; m < 4; m++)
    #pragma unroll
    for (int n = 0; n < 4; n++)
      acc[m][n] = f32x4{0.f, 0.f, 0.f, 0.f};

  for (int ks = 0; ks < KSTEPS; ks++) {
    __syncthreads();                     // prev tile's ds_reads complete
    #pragma unroll
    for (int c = 0; c < 4; c++) {
      const int row = w * 32 + c * 8 + srow;
      gload_lds16(Ab + (long)row * lda + ks * 64 + scol, At + (w * 4 + c) * 512);
      gload_lds16(Bb + (long)row * ldb + ks * 64 + scol, Bt + (w * 4 + c) * 512);
    }
    __syncthreads();                     // compiler drains vmcnt(0) before barrier
    #pragma unroll
    for (int kk = 0; kk < 2; kk++) {
      s16x8 af[4], bfr[4];
      #pragma unroll
      for (int m = 0; m < 4; m++)
        af[m] = *(const s16x8*)(At + (wr + m * 16 + fl) * 64 + ((kk * 32 + fh * 8) ^ swz));
      #pragma unroll
      for (int n = 0; n < 4; n++)
        bfr[n] = *(const s16x8*)(Bt + (wc + n * 16 + fl) * 64 + ((kk * 32 + fh * 8) ^ swz));
      #pragma unroll
      for (int m = 0; m < 4; m++)
        #pragma unroll
        for (int n = 0; n < 4; n++)
          acc[m][n] = __builtin_amdgcn_mfma_f32_16x16x32_bf16(af[m], bfr[n], acc[m][n], 0, 0, 0);
    }
  }
  #pragma unroll
  for (int m = 0; m < 4; m++) {
    const int r0 = wr + m * 16 + fh * 4;
    #pragma unroll
    for (int n = 0; n < 4; n++) {
      const int col = wc + n * 16 + fl;
      float bvv = 0.f;
      if constexpr (EPI == 1) bvv = biasb[col];
      f32x4 v = acc[m][n];
      #pragma unroll
      for (int r = 0; r < 4; r++) {
        float xv = v[r];
        if constexpr (EPI == 1) xv = fmaxf(xv + bvv, 0.f);
        Cb[(long)(r0 + r) * ldc + col] = f2bf(xv);
      }
    }
  }
}

// ---------------- fused GEMM3 + heads ----------------
// hidden = relu(feat @ [W1|V1] + [b1|vb1]) never hits HBM; epilogue applies
// W2/b2 softmax (actor) and V2/vb2 (critic) directly.
// 1024 threads = 16 waves (2 wave-rows x 8 wave-cols of 64x64), BM=128,
// BN=512 (full N in-block => A read exactly once), BK=64, K=512.
__global__ __launch_bounds__(1024, 2)
void gemm3_heads(const u16* __restrict__ A,        // feat [NROWS][512]
                 const u16* __restrict__ B,        // W1V1_t [512][512]
                 const float* __restrict__ b1vb1,  // [512]
                 const float* __restrict__ W2,     // [256][5]
                 const float* __restrict__ b2,     // [5]
                 const float* __restrict__ V2,     // [256]
                 const float* __restrict__ vb2,    // [1]
                 float* __restrict__ out)          // [NROWS][6]
{
  __shared__ __align__(16) u16 At[128 * 64];
  __shared__ __align__(16) u16 Bt[512 * 64];
  __shared__ float pstage[8][128][6];
  const int tid = threadIdx.x;
  const int w = tid >> 6, lane = tid & 63;
  const int fl = lane & 15, fh = lane >> 4;
  const int wrow = w >> 3, wcol = w & 7;
  const int srow = lane >> 3;
  const int schunk = (((lane & 7) ^ srow) << 3);
  const int swz = (fl & 7) << 3;

  const u16* Ab = A + (long)blockIdx.x * 128 * 512;

  f32x4 acc[4][4];
  #pragma unroll
  for (int m = 0; m < 4; m++)
    #pragma unroll
    for (int n = 0; n < 4; n++)
      acc[m][n] = f32x4{0.f, 0.f, 0.f, 0.f};

  for (int ks = 0; ks < 8; ks++) {
    __syncthreads();
    // A tile 128x64: one pass (16 waves x 8 rows)
    gload_lds16(Ab + (long)(w * 8 + srow) * 512 + ks * 64 + schunk, At + w * 512);
    // B tile 512x64: 4 passes
    #pragma unroll
    for (int p = 0; p < 4; p++)
      gload_lds16(B + (long)(p * 128 + w * 8 + srow) * 512 + ks * 64 + schunk,
                  Bt + p * 8192 + w * 512);
    __syncthreads();
    #pragma unroll
    for (int kk = 0; kk < 2; kk++) {
      s16x8 af[4], bfr[4];
      #pragma unroll
      for (int m = 0; m < 4; m++)
        af[m] = *(const s16x8*)(At + (wrow * 64 + m * 16 + fl) * 64 + ((kk * 32 + fh * 8) ^ swz));
      #pragma unroll
      for (int n = 0; n < 4; n++)
        bfr[n] = *(const s16x8*)(Bt + (wcol * 64 + n * 16 + fl) * 64 + ((kk * 32 + fh * 8) ^ swz));
      #pragma unroll
      for (int m = 0; m < 4; m++)
        #pragma unroll
        for (int n = 0; n < 4; n++)
          acc[m][n] = __builtin_amdgcn_mfma_f32_16x16x32_bf16(af[m], bfr[n], acc[m][n], 0, 0, 0);
    }
  }

  // ---- epilogue: relu(acc+b1) -> partial dots with W2/V2 -> LDS stage ----
  float bv[4];
  #pragma unroll
  for (int n = 0; n < 4; n++) bv[n] = b1vb1[wcol * 64 + n * 16 + fl];

  if (wcol < 4) {           // actor half: hid cols 0..255
    #pragma unroll
    for (int m = 0; m < 4; m++) {
      float ps[4][5];
      #pragma unroll
      for (int r = 0; r < 4; r++)
        #pragma unroll
        for (int j = 0; j < 5; j++) ps[r][j] = 0.f;
      #pragma unroll
      for (int n = 0; n < 4; n++) {
        const int col = wcol * 64 + n * 16 + fl;
        const float* w2c = W2 + col * 5;
        float w2r[5];
        #pragma unroll
        for (int j = 0; j < 5; j++) w2r[j] = w2c[j];
        #pragma unroll
        for (int r = 0; r < 4; r++) {
          float hid = fmaxf(acc[m][n][r] + bv[n], 0.f);
          #pragma unroll
          for (int j = 0; j < 5; j++) ps[r][j] += hid * w2r[j];
        }
      }
      #pragma unroll
      for (int off = 1; off < 16; off <<= 1)
        #pragma unroll
        for (int r = 0; r < 4; r++)
          #pragma unroll
          for (int j = 0; j < 5; j++) ps[r][j] += __shfl_xor(ps[r][j], off, 16);
      if (fl == 0) {
        const int row = wrow * 64 + m * 16 + fh * 4;
        #pragma unroll
        for (int r = 0; r < 4; r++)
          #pragma unroll
          for (int j = 0; j < 5; j++) pstage[wcol][row + r][j] = ps[r][j];
      }
    }
  } else {                  // critic half: hid cols 256..511
    #pragma unroll
    for (int m = 0; m < 4; m++) {
      float ps[4];
      #pragma unroll
      for (int r = 0; r < 4; r++) ps[r] = 0.f;
      #pragma unroll
      for (int n = 0; n < 4; n++) {
        const int col = wcol * 64 + n * 16 + fl;
        const float v2c = V2[col - 256];
        #pragma unroll
        for (int r = 0; r < 4; r++) {
          float hid = fmaxf(acc[m][n][r] + bv[n], 0.f);
          ps[r] += hid * v2c;
        }
      }
      #pragma unroll
      for (int off = 1; off < 16; off <<= 1)
        #pragma unroll
        for (int r = 0; r < 4; r++) ps[r] += __shfl_xor(ps[r], off, 16);
      if (fl == 0) {
        const int row = wrow * 64 + m * 16 + fh * 4;
        #pragma unroll
        for (int r = 0; r < 4; r++) pstage[wcol][row + r][5] = ps[r];
      }
    }
  }
  __syncthreads();

  // ---- final: softmax(5) | value, one thread per row ----
  if (tid < 128) {
    float lg[5];
    #pragma unroll
    for (int j = 0; j < 5; j++)
      lg[j] = pstage[0][tid][j] + pstage[1][tid][j] + pstage[2][tid][j] +
              pstage[3][tid][j] + b2[j];
    float val = pstage[4][tid][5] + pstage[5][tid][5] + pstage[6][tid][5] +
                pstage[7][tid][5] + vb2[0];
    float mx = -1e30f;
    #pragma unroll
    for (int j = 0; j < 5; j++) mx = fmaxf(mx, lg[j]);
    float s = 0.f, e[5];
    #pragma unroll
    for (int j = 0; j < 5; j++) { e[j] = __expf(lg[j] - mx); s += e[j]; }
    float inv = 1.f / s;
    float* op = out + ((long)blockIdx.x * 128 + tid) * 6;
    #pragma unroll
    for (int j = 0; j < 5; j++) op[j] = e[j] * inv;
    op[5] = val;
  }
}

// ---------------- per-graph attention + gat, writes feat cols 256..511 --------
// el/er arrive as Wh columns 250/251 (lane 62, q=2/3) — no reductions needed.
__global__ __launch_bounds__(256)
void attn_gat(const u16* __restrict__ Wh, u16* __restrict__ feat)
{
  const int w = threadIdx.x >> 6, lane = threadIdx.x & 63;
  const long g = (long)blockIdx.x * 4 + w;   // one wave per graph
  const int c0 = lane * 4;                    // 4 cols per lane (0..255)

  u64 raw[3][6];
  #pragma unroll
  for (int h = 0; h < 3; h++)
    #pragma unroll
    for (int i = 0; i < 6; i++)
      raw[h][i] = *(const u64*)(Wh + (((long)h * NROWS + g * 6 + i) << 8) + c0);

  float gacc[6][4];
  #pragma unroll
  for (int i = 0; i < 6; i++)
    #pragma unroll
    for (int q = 0; q < 4; q++) gacc[i][q] = 0.f;

  #pragma unroll
  for (int h = 0; h < 3; h++) {
    float whf[6][4];
    #pragma unroll
    for (int i = 0; i < 6; i++) {
      u64 v = raw[h][i];
      whf[i][0] = bf2f((u16)v);
      whf[i][1] = bf2f((u16)(v >> 16));
      whf[i][2] = bf2f((u16)(v >> 32));
      whf[i][3] = bf2f((u16)(v >> 48));
    }
    float el[6], er[6];
    #pragma unroll
    for (int i = 0; i < 6; i++) {
      el[i] = __shfl(whf[i][2], 62, 64);   // col 250
      er[i] = __shfl(whf[i][3], 62, 64);   // col 251
    }
    #pragma unroll
    for (int i = 0; i < 6; i++) {
      float e[6]; float mx = -1e30f;
      #pragma unroll
      for (int j = 0; j < 6; j++) {
        float t = el[i] + er[j];
        t = (t > 0.f) ? t : 0.2f * t;      // leaky_relu 0.2
        e[j] = t; mx = fmaxf(mx, t);
      }
      float s = 0.f;
      #pragma unroll
      for (int j = 0; j < 6; j++) { e[j] = __expf(e[j] - mx); s += e[j]; }
      float inv = 1.f / s;
      #pragma unroll
      for (int j = 0; j < 6; j++) {
        float a = e[j] * inv;
        #pragma unroll
        for (int q = 0; q < 4; q++) gacc[i][q] += a * whf[j][q];
      }
    }
  }
  #pragma unroll
  for (int i = 0; i < 6; i++) {
    const float k = 1.f / 3.f;
    u64 o = (u64)f2bf(gacc[i][0] * k)
          | ((u64)f2bf(gacc[i][1] * k) << 16)
          | ((u64)f2bf(gacc[i][2] * k) << 32)
          | ((u64)f2bf(gacc[i][3] * k) << 48);
    *(u64*)(feat + (g * 6 + i) * LDF + 256 + c0) = o;
  }
}

// ---------------- launch ----------------
extern "C" void kernel_launch(void* const* d_in, const int* in_sizes, int n_in,
                              void* d_out, int out_size, void* d_ws, size_t ws_size,
                              hipStream_t stream)
{
  const float* x     = (const float*)d_in[0];
  const float* W_emb = (const float*)d_in[1];
  const float* b_emb = (const float*)d_in[2];
  const float* W_gat = (const float*)d_in[3];
  const float* a_l   = (const float*)d_in[4];
  const float* a_r   = (const float*)d_in[5];
  const float* W1    = (const float*)d_in[6];
  const float* b1    = (const float*)d_in[7];
  const float* W2    = (const float*)d_in[8];
  const float* b2    = (const float*)d_in[9];
  const float* V1    = (const float*)d_in[10];
  const float* vb1   = (const float*)d_in[11];
  const float* V2    = (const float*)d_in[12];
  const float* vb2   = (const float*)d_in[13];

  char* ws = (char*)d_ws;
  u16* feat = (u16*)ws;                       // [98304][512] bf16 = 100,663,296 B
  char* r2  = ws + 100663296L;                // shared region, lifetimes disjoint:
  u16* xb   = (u16*)r2;                       //   [98304][128] (cvt_x -> gemm1)
  u16* Whb  = (u16*)r2;                       //   [3][98304][256] (gemm2 -> attn)
  char* wt  = r2 + 150994944L;
  u16*   Wemb_t = (u16*)wt;                   // 256*128
  u16*   Wgat_t = (u16*)(wt + 65536);         // 3*256*256
  u16*   W1V1_t = (u16*)(wt + 458752);        // 512*512
  float* b1vb1  = (float*)(wt + 983040);      // 512
  float* bembp  = (float*)(wt + 985088);      // 256

  prep_weights<<<256, 256, 0, stream>>>(W_emb, b_emb, W_gat, a_l, a_r, W1, b1, V1, vb1,
                                        Wemb_t, Wgat_t, W1V1_t, bembp, b1vb1);
  cvt_x<<<2048, 256, 0, stream>>>(x, xb);
  // h = relu(x @ W_emb + b) -> feat[:,0:256]   (grid: n fast, m slow)
  gemm_bf16<2, 1><<<dim3(2, 768), 256, 0, stream>>>(xb, 128, Wemb_t, 128, 0L,
                                                    feat, 512, 0L, bembp, 2);
  // Wh[h] = h @ W_gat[h]  (3 heads via z packed in grid.x); cols 250/251 = el/er
  gemm_bf16<4, 0><<<dim3(6, 768), 256, 0, stream>>>(feat, 512, Wgat_t, 256, 65536L,
                                                    Whb, 256, 25165824L, bembp, 2);
  // attention + gat -> feat[:,256:512]
  attn_gat<<<4096, 256, 0, stream>>>(Whb, feat);
  // fused: hidden = relu(feat @ [W1|V1] + [b1|vb1]); probs/value -> out
  gemm3_heads<<<768, 1024, 0, stream>>>(feat, W1V1_t, b1vb1, W2, b2, V2, vb2,
                                        (float*)d_out);
}